// Round 2
// baseline (5667.543 us; speedup 1.0000x reference)
//
#include <hip/hip_runtime.h>

// ---------- bf16 helpers ----------
__device__ __forceinline__ float bf2f(unsigned short u){
    union { unsigned int i; float f; } v; v.i = ((unsigned int)u) << 16; return v.f;
}
__device__ __forceinline__ unsigned short f2bf(float f){
    union { unsigned int i; float f; } v; v.f = f;
    unsigned int i = v.i;
    unsigned int r = i + 0x7FFFu + ((i >> 16) & 1u);   // round-nearest-even
    return (unsigned short)(r >> 16);
}
__device__ __forceinline__ float sigm(float x){ return 1.0f / (1.0f + __expf(-x)); }

// flag-dispatched scalar load: fF=1 -> fp32, fF=0 -> bf16
__device__ __forceinline__ float ldsel(const void* p, size_t idx, int fF){
    float r;
    if (fF) r = ((const float*)p)[idx];
    else    r = bf2f(((const unsigned short*)p)[idx]);
    return r;
}

typedef __attribute__((ext_vector_type(8))) short s8v;   // 8 bf16 (4 VGPRs)
typedef __attribute__((ext_vector_type(4))) float f4v;   // 4 fp32 accum

// ---------------------------------------------------------------------------
// k_detect: flags[0]=1 if float tensors are fp32 (else bf16);
//           flags[1]=1 if edge_index is int64 (else int32).
__global__ void k_detect(const unsigned short* __restrict__ X,
                         const int* __restrict__ ei, int* __restrict__ flags){
    __shared__ int cnt, nz;
    if (threadIdx.x == 0){ cnt = 0; nz = 0; }
    __syncthreads();
    int ok = 0;
    for (int i = threadIdx.x; i < 2048; i += 256){
        int e = (X[i] >> 7) & 0xFF;
        if (e >= 96 && e <= 160) ok++;
    }
    atomicAdd(&cnt, ok);
    int nzl = 0;
    for (int i = threadIdx.x; i < 128; i += 256)
        if (ei[2*i + 1] != 0) nzl++;
    atomicAdd(&nz, nzl);
    __syncthreads();
    if (threadIdx.x == 0){
        flags[0] = (cnt < 1843) ? 1 : 0;   // <90% plausible-bf16 => fp32
        flags[1] = (nz == 0)   ? 1 : 0;    // all odd int32 words zero => int64
    }
}

// ---------------------------------------------------------------------------
__global__ void k_deg(const int* __restrict__ ei, const void* __restrict__ ew,
                      float* __restrict__ deg, const int* __restrict__ flags,
                      int E, int N){
    int e = blockIdx.x * blockDim.x + threadIdx.x;
    if (e >= E) return;
    int fF = flags[0], fI = flags[1];
    int d = fI ? ei[2*(size_t)E + 2*(size_t)e] : ei[(size_t)E + e];
    if ((unsigned)d >= (unsigned)N) return;
    float w = ldsel(ew, e, fF);
    atomicAdd(&deg[d], w);
}

__global__ void k_dis(const float* __restrict__ deg, float* __restrict__ dis, int n){
    int t = blockIdx.x * blockDim.x + threadIdx.x;
    if (t < n){ float d = deg[t]; dis[t] = (d > 0.f) ? rsqrtf(d) : 0.f; }
}

// ---------------------------------------------------------------------------
struct PackArgs {
    const void* Wx[4];
    const void* Wh[4];
    const void* bx[4];
    const void* bh[4];
};

// Pack W = [Wx_g ; Wh_g] (256 x 128 per gate) into MFMA B-operand lane order:
// Bp[g*32768 + ct*4096 + kb*512 + lane*8 + j] = W[kb*32+(lane>>4)*8+j][ct*16+(lane&15)]
__global__ void k_pack(PackArgs pa, unsigned short* __restrict__ Bp,
                       float* __restrict__ bias, const int* __restrict__ flags){
    int t = blockIdx.x * blockDim.x + threadIdx.x;
    int fF = flags[0];
    if (t < 4*8*8*64*8){
        int j    =  t        & 7;
        int lane = (t >> 3)  & 63;
        int kb   = (t >> 9)  & 7;
        int ct   = (t >> 12) & 7;
        int g    = (t >> 15) & 3;
        int k   = kb*32 + (lane >> 4)*8 + j;
        int col = ct*16 + (lane & 15);
        const void* p; size_t idx;
        if (k < 128){ p = pa.Wx[g]; idx = (size_t)k*128 + col; }
        else        { p = pa.Wh[g]; idx = (size_t)(k-128)*128 + col; }
        unsigned short v;
        if (fF) v = f2bf(((const float*)p)[idx]);
        else    v = ((const unsigned short*)p)[idx];
        Bp[t] = v;
    }
    if (t < 512){
        int g = t >> 7, c = t & 127;
        bias[t] = ldsel(pa.bx[g], c, fF) + ldsel(pa.bh[g], c, fF);
    }
}

// ---------------------------------------------------------------------------
// k_prop: AX[d] += norm*X[s], AH[d] += norm*H[s].  32 threads/edge, 4 ch each.
__global__ void k_prop(const int* __restrict__ ei, const void* __restrict__ ew,
                       const float* __restrict__ dis,
                       const void* __restrict__ X, const void* __restrict__ H,
                       float* __restrict__ AX, float* __restrict__ AH,
                       const int* __restrict__ flags, int E, int N){
    long long t = (long long)blockIdx.x * blockDim.x + threadIdx.x;
    int e = (int)(t >> 5);
    if (e >= E) return;
    int c0 = ((int)t & 31) * 4;
    int fF = flags[0], fI = flags[1];
    int s, d;
    if (fI){ s = ei[2*(size_t)e]; d = ei[2*(size_t)E + 2*(size_t)e]; }
    else   { s = ei[e];           d = ei[(size_t)E + e]; }
    if ((unsigned)s >= (unsigned)N || (unsigned)d >= (unsigned)N) return;
    float w = ldsel(ew, e, fF);
    float nrm = dis[s] * w * dis[d];
    float x0,x1,x2,x3,h0,h1,h2,h3;
    if (fF){
        const float* xp = (const float*)X + (size_t)s*128 + c0;
        const float* hp = (const float*)H + (size_t)s*128 + c0;
        float4 xv = *(const float4*)xp;
        float4 hv = *(const float4*)hp;
        x0=xv.x; x1=xv.y; x2=xv.z; x3=xv.w;
        h0=hv.x; h1=hv.y; h2=hv.z; h3=hv.w;
    } else {
        const unsigned short* xp = (const unsigned short*)X + (size_t)s*128 + c0;
        const unsigned short* hp = (const unsigned short*)H + (size_t)s*128 + c0;
        uint2 xv = *(const uint2*)xp;
        uint2 hv = *(const uint2*)hp;
        x0 = bf2f((unsigned short)(xv.x & 0xffff)); x1 = bf2f((unsigned short)(xv.x >> 16));
        x2 = bf2f((unsigned short)(xv.y & 0xffff)); x3 = bf2f((unsigned short)(xv.y >> 16));
        h0 = bf2f((unsigned short)(hv.x & 0xffff)); h1 = bf2f((unsigned short)(hv.x >> 16));
        h2 = bf2f((unsigned short)(hv.y & 0xffff)); h3 = bf2f((unsigned short)(hv.y >> 16));
    }
    float* axp = AX + (size_t)d*128 + c0;
    float* ahp = AH + (size_t)d*128 + c0;
    atomicAdd(axp+0, nrm * x0);
    atomicAdd(axp+1, nrm * x1);
    atomicAdd(axp+2, nrm * x2);
    atomicAdd(axp+3, nrm * x3);
    atomicAdd(ahp+0, nrm * h0);
    atomicAdd(ahp+1, nrm * h1);
    atomicAdd(ahp+2, nrm * h2);
    atomicAdd(ahp+3, nrm * h3);
}

// ---------------------------------------------------------------------------
struct EpiArgs {
    const void *C, *wci, *wcf, *wco, *bi, *bff, *bc, *bo;
};

// Fused GEMM + LSTM epilogue. Block = 256 thr = 4 waves; 16 nodes/block;
// wave g computes gate g's 16x128 pre-activation via 16x16x32 bf16 MFMA.
__global__ __launch_bounds__(256)
void k_gemm(const float* __restrict__ AX, const float* __restrict__ AH,
            const unsigned short* __restrict__ Bp, const float* __restrict__ bias,
            EpiArgs ea, void* __restrict__ outp, const int* __restrict__ flags, int N){
    __shared__ unsigned short Atile[16*264];
    __shared__ float pre[4][16][132];

    int tid  = threadIdx.x;
    int wave = tid >> 6, lane = tid & 63;
    int node0 = blockIdx.x * 16;
    int fF = flags[0];

    // stage A-tile (16 x 256) as bf16, fp32->bf16 on the fly
    for (int i = tid; i < 4096; i += 256){
        int nn = i >> 8, k = i & 255;
        float v = 0.f;
        if (node0 + nn < N)
            v = (k < 128) ? AX[(size_t)(node0+nn)*128 + k]
                          : AH[(size_t)(node0+nn)*128 + (k-128)];
        Atile[nn*264 + k] = f2bf(v);
    }
    __syncthreads();

    f4v acc[8];
#pragma unroll
    for (int ct = 0; ct < 8; ct++) acc[ct] = (f4v){0.f,0.f,0.f,0.f};

    const int g = wave;
    const unsigned short* arow = &Atile[(lane & 15)*264 + (lane >> 4)*8];
#pragma unroll
    for (int kb = 0; kb < 8; kb++){
        s8v af = *(const s8v*)(arow + kb*32);
        const unsigned short* bbase = Bp + g*32768 + kb*512 + lane*8;
#pragma unroll
        for (int ct = 0; ct < 8; ct++){
            s8v bfrag = *(const s8v*)(bbase + ct*4096);
            acc[ct] = __builtin_amdgcn_mfma_f32_16x16x32_bf16(af, bfrag, acc[ct], 0, 0, 0);
        }
    }

    // D layout: col = lane&15, row = (lane>>4)*4 + r
    int q = lane >> 4, cl = lane & 15;
#pragma unroll
    for (int ct = 0; ct < 8; ct++){
        int col = ct*16 + cl;
        float bv = bias[g*128 + col];
#pragma unroll
        for (int r = 0; r < 4; r++)
            pre[g][q*4 + r][col] = acc[ct][r] + bv;
    }
    __syncthreads();

    // LSTM cell epilogue
    for (int i = tid; i < 2048; i += 256){
        int nn = i >> 7, c = i & 127;
        if (node0 + nn >= N) break;
        size_t gidx = (size_t)(node0+nn)*128 + c;
        float Cv  = ldsel(ea.C, gidx, fF);
        float pi  = pre[0][nn][c], pf = pre[1][nn][c];
        float pcv = pre[2][nn][c], po = pre[3][nn][c];
        float Iv = sigm(pi + ldsel(ea.wci, c, fF)*Cv + ldsel(ea.bi, c, fF));
        float Fv = sigm(pf + ldsel(ea.wcf, c, fF)*Cv + ldsel(ea.bff, c, fF));
        float Tv = tanhf(pcv + ldsel(ea.bc, c, fF));
        float Cn = Fv*Cv + Iv*Tv;
        float Ov = sigm(po + ldsel(ea.wco, c, fF)*Cn + ldsel(ea.bo, c, fF));
        float Hn = Ov * tanhf(Cn);
        if (fF){
            ((float*)outp)[gidx] = Hn;
            ((float*)outp)[(size_t)N*128 + gidx] = Cn;
        } else {
            ((unsigned short*)outp)[gidx] = f2bf(Hn);
            ((unsigned short*)outp)[(size_t)N*128 + gidx] = f2bf(Cn);
        }
    }
}

// ---------------------------------------------------------------------------
extern "C" void kernel_launch(void* const* d_in, const int* in_sizes, int n_in,
                              void* d_out, int out_size, void* d_ws, size_t ws_size,
                              hipStream_t stream){
    const void* X  = d_in[0];
    const int*  ei = (const int*)d_in[1];
    const void* ew = d_in[2];
    const void* H  = d_in[3];
    const void* C  = d_in[4];
    const int N = in_sizes[0] / 128;
    const int E = in_sizes[2];

    // workspace layout (bytes):
    // [0,1M) deg | [1M,27M) AX | [27M,53M) AH | [53M,54M) dis
    // [54M,+256K) Bp | [54M+512K] bias(2K) | [55M] flags(8B)
    char* ws = (char*)d_ws;
    float* deg          = (float*)(ws);
    float* AX           = (float*)(ws + ((size_t)1  << 20));
    float* AH           = (float*)(ws + ((size_t)27 << 20));
    float* dis          = (float*)(ws + ((size_t)53 << 20));
    unsigned short* Bp  = (unsigned short*)(ws + ((size_t)54 << 20));
    float* bias         = (float*)(ws + ((size_t)54 << 20) + ((size_t)1 << 19));
    int*   flags        = (int*)(ws + ((size_t)55 << 20));

    hipMemsetAsync(d_ws, 0, (size_t)53 << 20, stream);

    k_detect<<<1, 256, 0, stream>>>((const unsigned short*)X, ei, flags);
    k_deg<<<(E + 255)/256, 256, 0, stream>>>(ei, ew, deg, flags, E, N);
    k_dis<<<(N + 255)/256, 256, 0, stream>>>(deg, dis, N);

    PackArgs pa;
    pa.Wx[0]=d_in[5];  pa.bx[0]=d_in[6];  pa.Wh[0]=d_in[7];  pa.bh[0]=d_in[8];
    pa.Wx[1]=d_in[9];  pa.bx[1]=d_in[10]; pa.Wh[1]=d_in[11]; pa.bh[1]=d_in[12];
    pa.Wx[2]=d_in[13]; pa.bx[2]=d_in[14]; pa.Wh[2]=d_in[15]; pa.bh[2]=d_in[16];
    pa.Wx[3]=d_in[17]; pa.bx[3]=d_in[18]; pa.Wh[3]=d_in[19]; pa.bh[3]=d_in[20];
    k_pack<<<(131072 + 255)/256, 256, 0, stream>>>(pa, Bp, bias, flags);

    k_prop<<<(int)(((long long)E*32 + 255)/256), 256, 0, stream>>>(
        ei, ew, dis, X, H, AX, AH, flags, E, N);

    EpiArgs ea;
    ea.C   = C;
    ea.wci = d_in[21];
    ea.wcf = d_in[22];
    ea.wco = d_in[23];
    ea.bi  = d_in[24];
    ea.bff = d_in[25];
    ea.bc  = d_in[26];
    ea.bo  = d_in[27];
    k_gemm<<<(N + 15)/16, 256, 0, stream>>>(AX, AH, Bp, bias, ea, d_out, flags, N);
}

// Round 3
// 811.055 us; speedup vs baseline: 6.9879x; 6.9879x over previous
//
#include <hip/hip_runtime.h>

// ---------- bf16 helpers ----------
__device__ __forceinline__ float bf2f(unsigned short u){
    union { unsigned int i; float f; } v; v.i = ((unsigned int)u) << 16; return v.f;
}
__device__ __forceinline__ unsigned short f2bf(float f){
    union { unsigned int i; float f; } v; v.f = f;
    unsigned int i = v.i;
    unsigned int r = i + 0x7FFFu + ((i >> 16) & 1u);   // round-nearest-even
    return (unsigned short)(r >> 16);
}
__device__ __forceinline__ float sigm(float x){ return 1.0f / (1.0f + __expf(-x)); }

// flag-dispatched scalar load: fF=1 -> fp32, fF=0 -> bf16
__device__ __forceinline__ float ldsel(const void* p, size_t idx, int fF){
    float r;
    if (fF) r = ((const float*)p)[idx];
    else    r = bf2f(((const unsigned short*)p)[idx]);
    return r;
}

typedef __attribute__((ext_vector_type(8))) short s8v;   // 8 bf16 (4 VGPRs)
typedef __attribute__((ext_vector_type(4))) float f4v;   // 4 fp32 accum

// ---------------------------------------------------------------------------
// k_detect: flags[0]=1 if float tensors are fp32 (else bf16);
//           flags[1]=1 if edge_index is int64 (else int32).
__global__ void k_detect(const unsigned short* __restrict__ X,
                         const int* __restrict__ ei, int* __restrict__ flags){
    __shared__ int cnt, nz;
    if (threadIdx.x == 0){ cnt = 0; nz = 0; }
    __syncthreads();
    int ok = 0;
    for (int i = threadIdx.x; i < 2048; i += 256){
        int e = (X[i] >> 7) & 0xFF;
        if (e >= 96 && e <= 160) ok++;
    }
    atomicAdd(&cnt, ok);
    int nzl = 0;
    for (int i = threadIdx.x; i < 128; i += 256)
        if (ei[2*i + 1] != 0) nzl++;
    atomicAdd(&nz, nzl);
    __syncthreads();
    if (threadIdx.x == 0){
        flags[0] = (cnt < 1843) ? 1 : 0;   // <90% plausible-bf16 => fp32
        flags[1] = (nz == 0)   ? 1 : 0;    // all odd int32 words zero => int64
    }
}

// ---------------------------------------------------------------------------
// k_deg: deg[d] += w  AND  cnt[d] += 1
__global__ void k_deg(const int* __restrict__ ei, const void* __restrict__ ew,
                      float* __restrict__ deg, int* __restrict__ cnt,
                      const int* __restrict__ flags, int E, int N){
    int e = blockIdx.x * blockDim.x + threadIdx.x;
    if (e >= E) return;
    int fF = flags[0], fI = flags[1];
    int d = fI ? ei[2*(size_t)E + 2*(size_t)e] : ei[(size_t)E + e];
    if ((unsigned)d >= (unsigned)N) return;
    atomicAdd(&deg[d], ldsel(ew, e, fF));
    atomicAdd(&cnt[d], 1);
}

__global__ void k_dis(const float* __restrict__ deg, float* __restrict__ dis, int n){
    int t = blockIdx.x * blockDim.x + threadIdx.x;
    if (t < n){ float d = deg[t]; dis[t] = (d > 0.f) ? rsqrtf(d) : 0.f; }
}

// ---------------------------------------------------------------------------
// k_scan: single-block exclusive prefix sum of cnt[0..n) -> rowstart[0..n]
__global__ void k_scan(const int* __restrict__ cnt, int* __restrict__ rowstart, int n){
    __shared__ int part[256];
    int tid = threadIdx.x;
    int chunk = (n + 255) / 256;
    int b0 = tid * chunk;
    int b1 = min(b0 + chunk, n);
    int s = 0;
    for (int i = b0; i < b1; i++) s += cnt[i];
    part[tid] = s;
    __syncthreads();
    for (int off = 1; off < 256; off <<= 1){
        int v = (tid >= off) ? part[tid - off] : 0;
        __syncthreads();
        part[tid] += v;
        __syncthreads();
    }
    int base = (tid == 0) ? 0 : part[tid - 1];
    for (int i = b0; i < b1; i++){
        rowstart[i] = base;
        base += cnt[i];
    }
    if (tid == 255) rowstart[n] = base;
}

// ---------------------------------------------------------------------------
// k_scatter: place {src, norm} record into CSR bin of dst
__global__ void k_scatter(const int* __restrict__ ei, const void* __restrict__ ew,
                          const float* __restrict__ dis, const int* __restrict__ rowstart,
                          int* __restrict__ cursor, int2* __restrict__ recs,
                          const int* __restrict__ flags, int E, int N){
    int e = blockIdx.x * blockDim.x + threadIdx.x;
    if (e >= E) return;
    int fF = flags[0], fI = flags[1];
    int s, d;
    if (fI){ s = ei[2*(size_t)e]; d = ei[2*(size_t)E + 2*(size_t)e]; }
    else   { s = ei[e];           d = ei[(size_t)E + e]; }
    if ((unsigned)d >= (unsigned)N) return;
    float nrm = 0.f; int ss = 0;
    if ((unsigned)s < (unsigned)N){
        nrm = dis[s] * ldsel(ew, e, fF) * dis[d];
        ss = s;
    }
    int pos = rowstart[d] + atomicAdd(&cursor[d], 1);
    union { float f; int i; } u; u.f = nrm;
    int2 r; r.x = ss; r.y = u.i;
    recs[pos] = r;
}

// ---------------------------------------------------------------------------
// k_gather: one wave per node. lane owns ch {2l,2l+1} of X and of H.
// Accumulates in fp32 regs, writes AXH row as bf16 (MFMA A-feed layout:
// AXH[node][0..127]=AX, [128..255]=AH, contiguous bf16).
__global__ __launch_bounds__(256)
void k_gather(const int2* __restrict__ recs, const int* __restrict__ rowstart,
              const void* __restrict__ X, const void* __restrict__ H,
              unsigned short* __restrict__ AXH, const int* __restrict__ flags, int N){
    int gw   = (blockIdx.x * 256 + threadIdx.x) >> 6;   // wave id = node
    int lane = threadIdx.x & 63;
    if (gw >= N) return;
    int fF  = flags[0];
    int beg = rowstart[gw], end = rowstart[gw + 1];
    float ax0 = 0.f, ax1 = 0.f, ah0 = 0.f, ah1 = 0.f;
    if (fF){
        const float2* xp = (const float2*)X;
        const float2* hp = (const float2*)H;
        for (int i = beg; i < end; i++){
            int2 r = recs[i];
            float nrm = __int_as_float(r.y);
            float2 xv = xp[(size_t)r.x * 64 + lane];
            float2 hv = hp[(size_t)r.x * 64 + lane];
            ax0 += nrm * xv.x; ax1 += nrm * xv.y;
            ah0 += nrm * hv.x; ah1 += nrm * hv.y;
        }
    } else {
        const unsigned int* xp = (const unsigned int*)X;
        const unsigned int* hp = (const unsigned int*)H;
        for (int i = beg; i < end; i++){
            int2 r = recs[i];
            float nrm = __int_as_float(r.y);
            unsigned int xv = xp[(size_t)r.x * 64 + lane];
            unsigned int hv = hp[(size_t)r.x * 64 + lane];
            ax0 += nrm * bf2f((unsigned short)(xv & 0xffff));
            ax1 += nrm * bf2f((unsigned short)(xv >> 16));
            ah0 += nrm * bf2f((unsigned short)(hv & 0xffff));
            ah1 += nrm * bf2f((unsigned short)(hv >> 16));
        }
    }
    unsigned int* orow = (unsigned int*)AXH;
    orow[(size_t)gw * 128 + lane]      = ((unsigned int)f2bf(ax1) << 16) | f2bf(ax0);
    orow[(size_t)gw * 128 + 64 + lane] = ((unsigned int)f2bf(ah1) << 16) | f2bf(ah0);
}

// ---------------------------------------------------------------------------
struct PackArgs {
    const void* Wx[4];
    const void* Wh[4];
    const void* bx[4];
    const void* bh[4];
};

// Pack W = [Wx_g ; Wh_g] (256 x 128 per gate) into MFMA B-operand lane order.
__global__ void k_pack(PackArgs pa, unsigned short* __restrict__ Bp,
                       float* __restrict__ bias, const int* __restrict__ flags){
    int t = blockIdx.x * blockDim.x + threadIdx.x;
    int fF = flags[0];
    if (t < 4*8*8*64*8){
        int j    =  t        & 7;
        int lane = (t >> 3)  & 63;
        int kb   = (t >> 9)  & 7;
        int ct   = (t >> 12) & 7;
        int g    = (t >> 15) & 3;
        int k   = kb*32 + (lane >> 4)*8 + j;
        int col = ct*16 + (lane & 15);
        const void* p; size_t idx;
        if (k < 128){ p = pa.Wx[g]; idx = (size_t)k*128 + col; }
        else        { p = pa.Wh[g]; idx = (size_t)(k-128)*128 + col; }
        unsigned short v;
        if (fF) v = f2bf(((const float*)p)[idx]);
        else    v = ((const unsigned short*)p)[idx];
        Bp[t] = v;
    }
    if (t < 512){
        int g = t >> 7, c = t & 127;
        bias[t] = ldsel(pa.bx[g], c, fF) + ldsel(pa.bh[g], c, fF);
    }
}

// ---------------------------------------------------------------------------
struct EpiArgs {
    const void *C, *wci, *wcf, *wco, *bi, *bff, *bc, *bo;
};

// Fused GEMM + LSTM epilogue. Block = 4 waves; 16 nodes/block; wave g = gate g.
// A-fragments loaded directly from AXH (bf16, MFMA-native row layout).
__global__ __launch_bounds__(256)
void k_gemm(const unsigned short* __restrict__ AXH,
            const unsigned short* __restrict__ Bp, const float* __restrict__ bias,
            EpiArgs ea, void* __restrict__ outp, const int* __restrict__ flags, int N){
    __shared__ float pre[4][16][132];

    int tid  = threadIdx.x;
    int wave = tid >> 6, lane = tid & 63;
    int node0 = blockIdx.x * 16;
    int fF = flags[0];

    f4v acc[8];
#pragma unroll
    for (int ct = 0; ct < 8; ct++) acc[ct] = (f4v){0.f,0.f,0.f,0.f};

    const int g = wave;
    const unsigned short* abase = AXH + (size_t)(node0 + (lane & 15))*256 + (lane >> 4)*8;
#pragma unroll
    for (int kb = 0; kb < 8; kb++){
        s8v af = *(const s8v*)(abase + kb*32);
        const unsigned short* bbase = Bp + g*32768 + kb*512 + lane*8;
#pragma unroll
        for (int ct = 0; ct < 8; ct++){
            s8v bfrag = *(const s8v*)(bbase + ct*4096);
            acc[ct] = __builtin_amdgcn_mfma_f32_16x16x32_bf16(af, bfrag, acc[ct], 0, 0, 0);
        }
    }

    // D layout: col = lane&15, row = (lane>>4)*4 + r
    int q = lane >> 4, cl = lane & 15;
#pragma unroll
    for (int ct = 0; ct < 8; ct++){
        int col = ct*16 + cl;
        float bv = bias[g*128 + col];
#pragma unroll
        for (int r = 0; r < 4; r++)
            pre[g][q*4 + r][col] = acc[ct][r] + bv;
    }
    __syncthreads();

    // LSTM cell epilogue
    for (int i = tid; i < 2048; i += 256){
        int nn = i >> 7, c = i & 127;
        if (node0 + nn >= N) break;
        size_t gidx = (size_t)(node0+nn)*128 + c;
        float Cv  = ldsel(ea.C, gidx, fF);
        float pi  = pre[0][nn][c], pf = pre[1][nn][c];
        float pcv = pre[2][nn][c], po = pre[3][nn][c];
        float Iv = sigm(pi + ldsel(ea.wci, c, fF)*Cv + ldsel(ea.bi, c, fF));
        float Fv = sigm(pf + ldsel(ea.wcf, c, fF)*Cv + ldsel(ea.bff, c, fF));
        float Tv = tanhf(pcv + ldsel(ea.bc, c, fF));
        float Cn = Fv*Cv + Iv*Tv;
        float Ov = sigm(po + ldsel(ea.wco, c, fF)*Cn + ldsel(ea.bo, c, fF));
        float Hn = Ov * tanhf(Cn);
        if (fF){
            ((float*)outp)[gidx] = Hn;
            ((float*)outp)[(size_t)N*128 + gidx] = Cn;
        } else {
            ((unsigned short*)outp)[gidx] = f2bf(Hn);
            ((unsigned short*)outp)[(size_t)N*128 + gidx] = f2bf(Cn);
        }
    }
}

// ---------------------------------------------------------------------------
extern "C" void kernel_launch(void* const* d_in, const int* in_sizes, int n_in,
                              void* d_out, int out_size, void* d_ws, size_t ws_size,
                              hipStream_t stream){
    const void* X  = d_in[0];
    const int*  ei = (const int*)d_in[1];
    const void* ew = d_in[2];
    const void* H  = d_in[3];
    const void* C  = d_in[4];
    const int N = in_sizes[0] / 128;
    const int E = in_sizes[2];

    // workspace layout (bytes):
    // [0,256K) deg | [256K,512K) cnt | [512K,768K) cursor | [768K,1M) dis
    // [1M,1.25M) rowstart | [1.25M] flags | [1.5M,1.75M) Bp | [1.8M] bias
    // [2M,14.8M) recs | [15M,40.7M) AXH
    char* ws = (char*)d_ws;
    float* deg          = (float*)(ws);
    int*   cnt          = (int*)  (ws + ((size_t)256 << 10));
    int*   cursor       = (int*)  (ws + ((size_t)512 << 10));
    float* dis          = (float*)(ws + ((size_t)768 << 10));
    int*   rowstart     = (int*)  (ws + ((size_t)1 << 20));
    int*   flags        = (int*)  (ws + ((size_t)1 << 20) + ((size_t)256 << 10));
    unsigned short* Bp  = (unsigned short*)(ws + ((size_t)1 << 20) + ((size_t)512 << 10));
    float* bias         = (float*)(ws + ((size_t)1 << 20) + ((size_t)820 << 10));
    int2*  recs         = (int2*) (ws + ((size_t)2 << 20));
    unsigned short* AXH = (unsigned short*)(ws + ((size_t)15 << 20));

    // zero deg + cnt + cursor only
    hipMemsetAsync(d_ws, 0, (size_t)768 << 10, stream);

    k_detect<<<1, 256, 0, stream>>>((const unsigned short*)X, ei, flags);
    k_deg<<<(E + 255)/256, 256, 0, stream>>>(ei, ew, deg, cnt, flags, E, N);
    k_dis<<<(N + 255)/256, 256, 0, stream>>>(deg, dis, N);
    k_scan<<<1, 256, 0, stream>>>(cnt, rowstart, N);
    k_scatter<<<(E + 255)/256, 256, 0, stream>>>(ei, ew, dis, rowstart, cursor,
                                                 recs, flags, E, N);
    k_gather<<<(N*64 + 255)/256, 256, 0, stream>>>(recs, rowstart, X, H, AXH, flags, N);

    PackArgs pa;
    pa.Wx[0]=d_in[5];  pa.bx[0]=d_in[6];  pa.Wh[0]=d_in[7];  pa.bh[0]=d_in[8];
    pa.Wx[1]=d_in[9];  pa.bx[1]=d_in[10]; pa.Wh[1]=d_in[11]; pa.bh[1]=d_in[12];
    pa.Wx[2]=d_in[13]; pa.bx[2]=d_in[14]; pa.Wh[2]=d_in[15]; pa.bh[2]=d_in[16];
    pa.Wx[3]=d_in[17]; pa.bx[3]=d_in[18]; pa.Wh[3]=d_in[19]; pa.bh[3]=d_in[20];
    k_pack<<<(131072 + 255)/256, 256, 0, stream>>>(pa, Bp, bias, flags);

    EpiArgs ea;
    ea.C   = C;
    ea.wci = d_in[21];
    ea.wcf = d_in[22];
    ea.wco = d_in[23];
    ea.bi  = d_in[24];
    ea.bff = d_in[25];
    ea.bc  = d_in[26];
    ea.bo  = d_in[27];
    k_gemm<<<(N + 15)/16, 256, 0, stream>>>(AXH, Bp, bias, ea, d_out, flags, N);
}

// Round 4
// 634.374 us; speedup vs baseline: 8.9341x; 1.2785x over previous
//
#include <hip/hip_runtime.h>

// ---------- bf16 helpers ----------
__device__ __forceinline__ float bf2f(unsigned short u){
    union { unsigned int i; float f; } v; v.i = ((unsigned int)u) << 16; return v.f;
}
__device__ __forceinline__ unsigned short f2bf(float f){
    union { unsigned int i; float f; } v; v.f = f;
    unsigned int i = v.i;
    unsigned int r = i + 0x7FFFu + ((i >> 16) & 1u);   // round-nearest-even
    return (unsigned short)(r >> 16);
}
__device__ __forceinline__ float sigm(float x){ return 1.0f / (1.0f + __expf(-x)); }

// flag-dispatched scalar load: fF=1 -> fp32, fF=0 -> bf16
__device__ __forceinline__ float ldsel(const void* p, size_t idx, int fF){
    float r;
    if (fF) r = ((const float*)p)[idx];
    else    r = bf2f(((const unsigned short*)p)[idx]);
    return r;
}

typedef __attribute__((ext_vector_type(8))) short s8v;   // 8 bf16 (4 VGPRs)
typedef __attribute__((ext_vector_type(4))) float f4v;   // 4 fp32 accum

// ---------------------------------------------------------------------------
// k_detect: flags[0]=1 if float tensors are fp32 (else bf16);
//           flags[1]=1 if edge_index is int64 (else int32).
__global__ void k_detect(const unsigned short* __restrict__ X,
                         const int* __restrict__ ei, int* __restrict__ flags){
    __shared__ int cnt, nz;
    if (threadIdx.x == 0){ cnt = 0; nz = 0; }
    __syncthreads();
    int ok = 0;
    for (int i = threadIdx.x; i < 2048; i += 256){
        int e = (X[i] >> 7) & 0xFF;
        if (e >= 96 && e <= 160) ok++;
    }
    atomicAdd(&cnt, ok);
    int nzl = 0;
    for (int i = threadIdx.x; i < 128; i += 256)
        if (ei[2*i + 1] != 0) nzl++;
    atomicAdd(&nz, nzl);
    __syncthreads();
    if (threadIdx.x == 0){
        flags[0] = (cnt < 1843) ? 1 : 0;   // <90% plausible-bf16 => fp32
        flags[1] = (nz == 0)   ? 1 : 0;    // all odd int32 words zero => int64
    }
}

// ---------------------------------------------------------------------------
// k_tobf: build XHb[node][256] bf16 = [X row | H row]
__global__ void k_tobf(const void* __restrict__ X, const void* __restrict__ H,
                       unsigned int* __restrict__ XHb32,
                       const int* __restrict__ flags, int N){
    int t = blockIdx.x * 256 + threadIdx.x;
    if (t >= N * 64) return;
    int n = t >> 6, l = t & 63;
    int fF = flags[0];
    unsigned int xw, hw;
    if (fF){
        float2 xv = ((const float2*)X)[(size_t)n*64 + l];
        float2 hv = ((const float2*)H)[(size_t)n*64 + l];
        xw = ((unsigned int)f2bf(xv.y) << 16) | f2bf(xv.x);
        hw = ((unsigned int)f2bf(hv.y) << 16) | f2bf(hv.x);
    } else {
        xw = ((const unsigned int*)X)[(size_t)n*64 + l];
        hw = ((const unsigned int*)H)[(size_t)n*64 + l];
    }
    XHb32[(size_t)n*128 + l]      = xw;
    XHb32[(size_t)n*128 + 64 + l] = hw;
}

// ---------------------------------------------------------------------------
// k_cnt: off[e] = cnt[d]++   (the only atomic pass)
__global__ void k_cnt(const int* __restrict__ ei, int* __restrict__ cnt,
                      int* __restrict__ off, const int* __restrict__ flags,
                      int E, int N){
    int e = blockIdx.x * 256 + threadIdx.x;
    if (e >= E) return;
    int fI = flags[1];
    int d = fI ? ei[2*(size_t)E + 2*(size_t)e] : ei[(size_t)E + e];
    if ((unsigned)d >= (unsigned)N) return;
    off[e] = atomicAdd(&cnt[d], 1);
}

// ---------------------------------------------------------------------------
// parallel scan trio: rowstart = exclusive_scan(cnt), rowstart[n] = total
__global__ void k_scanA(const int* __restrict__ cnt, int* __restrict__ bsum, int n){
    __shared__ int sh[256];
    int t = threadIdx.x, i = blockIdx.x * 256 + t;
    sh[t] = (i < n) ? cnt[i] : 0;
    __syncthreads();
    for (int o = 128; o > 0; o >>= 1){
        if (t < o) sh[t] += sh[t + o];
        __syncthreads();
    }
    if (t == 0) bsum[blockIdx.x] = sh[0];
}
__global__ void k_scanB(const int* __restrict__ bsum, int* __restrict__ bsumoff, int nb){
    __shared__ int sh[256];
    int t = threadIdx.x;
    int v = (t < nb) ? bsum[t] : 0;
    sh[t] = v;
    __syncthreads();
    for (int o = 1; o < 256; o <<= 1){
        int u = (t >= o) ? sh[t - o] : 0;
        __syncthreads();
        sh[t] += u;
        __syncthreads();
    }
    bsumoff[t] = sh[t] - v;
}
__global__ void k_scanC(const int* __restrict__ cnt, const int* __restrict__ bsumoff,
                        int* __restrict__ rowstart, int n){
    __shared__ int sh[256];
    int t = threadIdx.x, i = blockIdx.x * 256 + t;
    int v = (i < n) ? cnt[i] : 0;
    sh[t] = v;
    __syncthreads();
    for (int o = 1; o < 256; o <<= 1){
        int u = (t >= o) ? sh[t - o] : 0;
        __syncthreads();
        sh[t] += u;
        __syncthreads();
    }
    int incl = sh[t];
    if (i < n)     rowstart[i] = bsumoff[blockIdx.x] + incl - v;
    if (i == n-1)  rowstart[n] = bsumoff[blockIdx.x] + incl;
}

// ---------------------------------------------------------------------------
// k_scatter: recs[rowstart[d]+off[e]] = {src, w}  (no atomics)
__global__ void k_scatter(const int* __restrict__ ei, const void* __restrict__ ew,
                          const int* __restrict__ rowstart, const int* __restrict__ off,
                          int2* __restrict__ recs, const int* __restrict__ flags,
                          int E, int N){
    int e = blockIdx.x * 256 + threadIdx.x;
    if (e >= E) return;
    int fF = flags[0], fI = flags[1];
    int s, d;
    if (fI){ s = ei[2*(size_t)e]; d = ei[2*(size_t)E + 2*(size_t)e]; }
    else   { s = ei[e];           d = ei[(size_t)E + e]; }
    if ((unsigned)d >= (unsigned)N) return;
    float w = 0.f; int ss = 0;
    if ((unsigned)s < (unsigned)N){ w = ldsel(ew, e, fF); ss = s; }
    int2 r; r.x = ss; r.y = __float_as_int(w);
    recs[rowstart[d] + off[e]] = r;
}

// ---------------------------------------------------------------------------
// k_degdis: one wave per node, deg = sum of w over bin (coalesced), dis = rsqrt
__global__ __launch_bounds__(256)
void k_degdis(const int2* __restrict__ recs, const int* __restrict__ rowstart,
              float* __restrict__ dis, int N){
    int gw = (blockIdx.x * 256 + threadIdx.x) >> 6;
    int lane = threadIdx.x & 63;
    if (gw >= N) return;
    int beg = rowstart[gw], end = rowstart[gw + 1];
    float sw = 0.f;
    for (int i = beg + lane; i < end; i += 64) sw += __int_as_float(recs[i].y);
    for (int o = 32; o > 0; o >>= 1) sw += __shfl_down(sw, o);
    if (lane == 0) dis[gw] = (sw > 0.f) ? rsqrtf(sw) : 0.f;
}

// ---------------------------------------------------------------------------
struct PackArgs {
    const void* Wx[4];
    const void* Wh[4];
    const void* bx[4];
    const void* bh[4];
};

// Pack W = [Wx_g ; Wh_g] (256 x 128 per gate) into MFMA B-operand lane order.
__global__ void k_pack(PackArgs pa, unsigned short* __restrict__ Bp,
                       float* __restrict__ bias, const int* __restrict__ flags){
    int t = blockIdx.x * blockDim.x + threadIdx.x;
    int fF = flags[0];
    if (t < 4*8*8*64*8){
        int j    =  t        & 7;
        int lane = (t >> 3)  & 63;
        int kb   = (t >> 9)  & 7;
        int ct   = (t >> 12) & 7;
        int g    = (t >> 15) & 3;
        int k   = kb*32 + (lane >> 4)*8 + j;
        int col = ct*16 + (lane & 15);
        const void* p; size_t idx;
        if (k < 128){ p = pa.Wx[g]; idx = (size_t)k*128 + col; }
        else        { p = pa.Wh[g]; idx = (size_t)(k-128)*128 + col; }
        unsigned short v;
        if (fF) v = f2bf(((const float*)p)[idx]);
        else    v = ((const unsigned short*)p)[idx];
        Bp[t] = v;
    }
    if (t < 512){
        int g = t >> 7, c = t & 127;
        bias[t] = ldsel(pa.bx[g], c, fF) + ldsel(pa.bh[g], c, fF);
    }
}

// ---------------------------------------------------------------------------
struct EpiArgs {
    const void *C, *wci, *wcf, *wco, *bi, *bff, *bc, *bo;
};

// Fused gather + GEMM + LSTM epilogue. Block = 4 waves, 16 nodes.
// Phase 1: each wave gathers 4 nodes' bins into the LDS A-tile (bf16).
//          recs/dis/rowstart reads forced to the scalar pipe via readfirstlane.
// Phase 2: wave g computes gate g's 16x128 pre via 16x16x32 bf16 MFMA.
// Phase 3: LSTM cell epilogue.
__global__ __launch_bounds__(256)
void k_gg(const int2* __restrict__ recs, const int* __restrict__ rowstart,
          const float* __restrict__ dis, const unsigned int* __restrict__ XHb32,
          const unsigned short* __restrict__ Bp, const float* __restrict__ bias,
          EpiArgs ea, void* __restrict__ outp, const int* __restrict__ flags, int N){
    __shared__ unsigned short Atile[16*264];
    __shared__ float pre[4][16][132];

    int tid  = threadIdx.x;
    int wave = tid >> 6, lane = tid & 63;
    int node0 = blockIdx.x * 16;
    int fF = flags[0];

    // ---- phase 1: gather ----
    for (int r = 0; r < 4; r++){
        int nn = wave*4 + r;
        int node = node0 + nn;
        float ax0=0.f, ax1=0.f, ah0=0.f, ah1=0.f;
        if (node < N){
            int beg  = __builtin_amdgcn_readfirstlane(rowstart[node]);
            int end  = __builtin_amdgcn_readfirstlane(rowstart[node + 1]);
            float disd = dis[node];
            for (int i = beg; i < end; i++){
                int2 rc = recs[i];
                int   s   = __builtin_amdgcn_readfirstlane(rc.x);
                float nrm = dis[s] * __int_as_float(rc.y) * disd;
                unsigned int xv = XHb32[(size_t)s*128 + lane];
                unsigned int hv = XHb32[(size_t)s*128 + 64 + lane];
                ax0 += nrm * bf2f((unsigned short)(xv & 0xffff));
                ax1 += nrm * bf2f((unsigned short)(xv >> 16));
                ah0 += nrm * bf2f((unsigned short)(hv & 0xffff));
                ah1 += nrm * bf2f((unsigned short)(hv >> 16));
            }
        }
        unsigned int* arow = (unsigned int*)(Atile + nn*264);
        arow[lane]      = ((unsigned int)f2bf(ax1) << 16) | f2bf(ax0);
        arow[64 + lane] = ((unsigned int)f2bf(ah1) << 16) | f2bf(ah0);
    }
    __syncthreads();

    // ---- phase 2: MFMA ----
    f4v acc[8];
#pragma unroll
    for (int ct = 0; ct < 8; ct++) acc[ct] = (f4v){0.f,0.f,0.f,0.f};

    const int g = wave;
    const unsigned short* arow = &Atile[(lane & 15)*264 + (lane >> 4)*8];
#pragma unroll
    for (int kb = 0; kb < 8; kb++){
        s8v af = *(const s8v*)(arow + kb*32);
        const unsigned short* bbase = Bp + g*32768 + kb*512 + lane*8;
#pragma unroll
        for (int ct = 0; ct < 8; ct++){
            s8v bfrag = *(const s8v*)(bbase + ct*4096);
            acc[ct] = __builtin_amdgcn_mfma_f32_16x16x32_bf16(af, bfrag, acc[ct], 0, 0, 0);
        }
    }

    // D layout: col = lane&15, row = (lane>>4)*4 + r
    int q = lane >> 4, cl = lane & 15;
#pragma unroll
    for (int ct = 0; ct < 8; ct++){
        int col = ct*16 + cl;
        float bv = bias[g*128 + col];
#pragma unroll
        for (int r = 0; r < 4; r++)
            pre[g][q*4 + r][col] = acc[ct][r] + bv;
    }
    __syncthreads();

    // ---- phase 3: LSTM epilogue ----
    for (int i = tid; i < 2048; i += 256){
        int nn = i >> 7, c = i & 127;
        if (node0 + nn >= N) break;
        size_t gidx = (size_t)(node0+nn)*128 + c;
        float Cv  = ldsel(ea.C, gidx, fF);
        float pi  = pre[0][nn][c], pf = pre[1][nn][c];
        float pcv = pre[2][nn][c], po = pre[3][nn][c];
        float Iv = sigm(pi + ldsel(ea.wci, c, fF)*Cv + ldsel(ea.bi, c, fF));
        float Fv = sigm(pf + ldsel(ea.wcf, c, fF)*Cv + ldsel(ea.bff, c, fF));
        float Tv = tanhf(pcv + ldsel(ea.bc, c, fF));
        float Cn = Fv*Cv + Iv*Tv;
        float Ov = sigm(po + ldsel(ea.wco, c, fF)*Cn + ldsel(ea.bo, c, fF));
        float Hn = Ov * tanhf(Cn);
        if (fF){
            ((float*)outp)[gidx] = Hn;
            ((float*)outp)[(size_t)N*128 + gidx] = Cn;
        } else {
            ((unsigned short*)outp)[gidx] = f2bf(Hn);
            ((unsigned short*)outp)[(size_t)N*128 + gidx] = f2bf(Cn);
        }
    }
}

// ---------------------------------------------------------------------------
extern "C" void kernel_launch(void* const* d_in, const int* in_sizes, int n_in,
                              void* d_out, int out_size, void* d_ws, size_t ws_size,
                              hipStream_t stream){
    const void* X  = d_in[0];
    const int*  ei = (const int*)d_in[1];
    const void* ew = d_in[2];
    const void* H  = d_in[3];
    const void* C  = d_in[4];
    const int N = in_sizes[0] / 128;
    const int E = in_sizes[2];

    // workspace layout (bytes), total < 48 MB:
    // [0,256K) cnt | [256K,512K) dis | [512K,768K) rowstart
    // [768K] bsum(1K) | [772K] bsumoff(1K) | [776K] flags(8B)
    // [1M,1.25M) Bp | [1.25M] bias(2K)
    // [2M,8.4M) off | [9M,21.8M) recs | [22M,47.6M) XHb
    char* ws = (char*)d_ws;
    int*   cnt          = (int*)  (ws);
    float* dis          = (float*)(ws + ((size_t)256 << 10));
    int*   rowstart     = (int*)  (ws + ((size_t)512 << 10));
    int*   bsum         = (int*)  (ws + ((size_t)768 << 10));
    int*   bsumoff      = (int*)  (ws + ((size_t)772 << 10));
    int*   flags        = (int*)  (ws + ((size_t)776 << 10));
    unsigned short* Bp  = (unsigned short*)(ws + ((size_t)1 << 20));
    float* bias         = (float*)(ws + ((size_t)1 << 20) + ((size_t)256 << 10));
    int*   off          = (int*)  (ws + ((size_t)2 << 20));
    int2*  recs         = (int2*) (ws + ((size_t)9 << 20));
    unsigned int* XHb32 = (unsigned int*)(ws + ((size_t)22 << 20));

    hipMemsetAsync(cnt, 0, (size_t)256 << 10, stream);

    k_detect<<<1, 256, 0, stream>>>((const unsigned short*)X, ei, flags);
    k_tobf<<<(N*64 + 255)/256, 256, 0, stream>>>(X, H, XHb32, flags, N);
    k_cnt<<<(E + 255)/256, 256, 0, stream>>>(ei, cnt, off, flags, E, N);

    int nbA = (N + 255)/256;
    k_scanA<<<nbA, 256, 0, stream>>>(cnt, bsum, N);
    k_scanB<<<1, 256, 0, stream>>>(bsum, bsumoff, nbA);
    k_scanC<<<nbA, 256, 0, stream>>>(cnt, bsumoff, rowstart, N);

    k_scatter<<<(E + 255)/256, 256, 0, stream>>>(ei, ew, rowstart, off, recs, flags, E, N);
    k_degdis<<<(N*64 + 255)/256, 256, 0, stream>>>(recs, rowstart, dis, N);

    PackArgs pa;
    pa.Wx[0]=d_in[5];  pa.bx[0]=d_in[6];  pa.Wh[0]=d_in[7];  pa.bh[0]=d_in[8];
    pa.Wx[1]=d_in[9];  pa.bx[1]=d_in[10]; pa.Wh[1]=d_in[11]; pa.bh[1]=d_in[12];
    pa.Wx[2]=d_in[13]; pa.bx[2]=d_in[14]; pa.Wh[2]=d_in[15]; pa.bh[2]=d_in[16];
    pa.Wx[3]=d_in[17]; pa.bx[3]=d_in[18]; pa.Wh[3]=d_in[19]; pa.bh[3]=d_in[20];
    k_pack<<<(131072 + 255)/256, 256, 0, stream>>>(pa, Bp, bias, flags);

    EpiArgs ea;
    ea.C   = C;
    ea.wci = d_in[21];
    ea.wcf = d_in[22];
    ea.wco = d_in[23];
    ea.bi  = d_in[24];
    ea.bff = d_in[25];
    ea.bc  = d_in[26];
    ea.bo  = d_in[27];
    k_gg<<<(N + 15)/16, 256, 0, stream>>>(recs, rowstart, dis, XHb32, Bp, bias,
                                          ea, d_out, flags, N);
}

// Round 5
// 589.203 us; speedup vs baseline: 9.6190x; 1.0767x over previous
//
#include <hip/hip_runtime.h>

// ---------- bf16 helpers ----------
__device__ __forceinline__ float bf2f(unsigned short u){
    union { unsigned int i; float f; } v; v.i = ((unsigned int)u) << 16; return v.f;
}
__device__ __forceinline__ unsigned short f2bf(float f){
    union { unsigned int i; float f; } v; v.f = f;
    unsigned int i = v.i;
    unsigned int r = i + 0x7FFFu + ((i >> 16) & 1u);   // round-nearest-even
    return (unsigned short)(r >> 16);
}
__device__ __forceinline__ float sigm(float x){ return 1.0f / (1.0f + __expf(-x)); }

// flag-dispatched scalar load: fF=1 -> fp32, fF=0 -> bf16
__device__ __forceinline__ float ldsel(const void* p, size_t idx, int fF){
    float r;
    if (fF) r = ((const float*)p)[idx];
    else    r = bf2f(((const unsigned short*)p)[idx]);
    return r;
}

typedef __attribute__((ext_vector_type(8))) short s8v;   // 8 bf16 (4 VGPRs)
typedef __attribute__((ext_vector_type(4))) float f4v;   // 4 fp32 accum

// ---------------------------------------------------------------------------
// k_detect: flags[0]=1 if float tensors are fp32 (else bf16);
//           flags[1]=1 if edge_index is int64 (else int32).
__global__ void k_detect(const unsigned short* __restrict__ X,
                         const int* __restrict__ ei, int* __restrict__ flags){
    __shared__ int cnt, nz;
    if (threadIdx.x == 0){ cnt = 0; nz = 0; }
    __syncthreads();
    int ok = 0;
    for (int i = threadIdx.x; i < 2048; i += 256){
        int e = (X[i] >> 7) & 0xFF;
        if (e >= 96 && e <= 160) ok++;
    }
    atomicAdd(&cnt, ok);
    int nzl = 0;
    for (int i = threadIdx.x; i < 128; i += 256)
        if (ei[2*i + 1] != 0) nzl++;
    atomicAdd(&nz, nzl);
    __syncthreads();
    if (threadIdx.x == 0){
        flags[0] = (cnt < 1843) ? 1 : 0;   // <90% plausible-bf16 => fp32
        flags[1] = (nz == 0)   ? 1 : 0;    // all odd int32 words zero => int64
    }
}

// ---------------------------------------------------------------------------
struct PackArgs {
    const void* Wx[4];
    const void* Wh[4];
    const void* bx[4];
    const void* bh[4];
};

// k_fused1: block-range-partitioned independent preamble.
//  blocks [0,nbT):          tobf  — XHb[node][256] bf16 = [X row | H row]
//  blocks [nbT,nbT+nbC):    cnt   — off[e] = cnt[d]++  (the only atomic pass)
//  blocks [nbT+nbC, +512):  pack  — W -> MFMA B lane order; bias = bx+bh
__global__ void k_fused1(const void* __restrict__ X, const void* __restrict__ H,
                         unsigned int* __restrict__ XHb32,
                         const int* __restrict__ ei, int* __restrict__ cnt,
                         int* __restrict__ off,
                         PackArgs pa, unsigned short* __restrict__ Bp,
                         float* __restrict__ bias,
                         const int* __restrict__ flags,
                         int nbT, int nbC, int E, int N){
    int b = blockIdx.x;
    int fF = flags[0];
    if (b < nbT){
        int t = b*256 + threadIdx.x;
        if (t >= N * 64) return;
        int n = t >> 6, l = t & 63;
        unsigned int xw, hw;
        if (fF){
            float2 xv = ((const float2*)X)[(size_t)n*64 + l];
            float2 hv = ((const float2*)H)[(size_t)n*64 + l];
            xw = ((unsigned int)f2bf(xv.y) << 16) | f2bf(xv.x);
            hw = ((unsigned int)f2bf(hv.y) << 16) | f2bf(hv.x);
        } else {
            xw = ((const unsigned int*)X)[(size_t)n*64 + l];
            hw = ((const unsigned int*)H)[(size_t)n*64 + l];
        }
        XHb32[(size_t)n*128 + l]      = xw;
        XHb32[(size_t)n*128 + 64 + l] = hw;
    } else if (b < nbT + nbC){
        int e = (b - nbT)*256 + threadIdx.x;
        if (e >= E) return;
        int fI = flags[1];
        int d = fI ? ei[2*(size_t)E + 2*(size_t)e] : ei[(size_t)E + e];
        if ((unsigned)d >= (unsigned)N) return;
        off[e] = atomicAdd(&cnt[d], 1);
    } else {
        int t = (b - nbT - nbC)*256 + threadIdx.x;
        if (t < 4*8*8*64*8){
            int j    =  t        & 7;
            int lane = (t >> 3)  & 63;
            int kb   = (t >> 9)  & 7;
            int ct   = (t >> 12) & 7;
            int g    = (t >> 15) & 3;
            int k   = kb*32 + (lane >> 4)*8 + j;
            int col = ct*16 + (lane & 15);
            const void* p; size_t idx;
            if (k < 128){ p = pa.Wx[g]; idx = (size_t)k*128 + col; }
            else        { p = pa.Wh[g]; idx = (size_t)(k-128)*128 + col; }
            unsigned short v;
            if (fF) v = f2bf(((const float*)p)[idx]);
            else    v = ((const unsigned short*)p)[idx];
            Bp[t] = v;
        }
        if (t < 512){
            int g = t >> 7, c = t & 127;
            bias[t] = ldsel(pa.bx[g], c, fF) + ldsel(pa.bh[g], c, fF);
        }
    }
}

// ---------------------------------------------------------------------------
// parallel scan trio: rowstart = exclusive_scan(cnt), rowstart[n] = total
__global__ void k_scanA(const int* __restrict__ cnt, int* __restrict__ bsum, int n){
    __shared__ int sh[256];
    int t = threadIdx.x, i = blockIdx.x * 256 + t;
    sh[t] = (i < n) ? cnt[i] : 0;
    __syncthreads();
    for (int o = 128; o > 0; o >>= 1){
        if (t < o) sh[t] += sh[t + o];
        __syncthreads();
    }
    if (t == 0) bsum[blockIdx.x] = sh[0];
}
__global__ void k_scanB(const int* __restrict__ bsum, int* __restrict__ bsumoff, int nb){
    __shared__ int sh[256];
    int t = threadIdx.x;
    int v = (t < nb) ? bsum[t] : 0;
    sh[t] = v;
    __syncthreads();
    for (int o = 1; o < 256; o <<= 1){
        int u = (t >= o) ? sh[t - o] : 0;
        __syncthreads();
        sh[t] += u;
        __syncthreads();
    }
    bsumoff[t] = sh[t] - v;
}
__global__ void k_scanC(const int* __restrict__ cnt, const int* __restrict__ bsumoff,
                        int* __restrict__ rowstart, int n){
    __shared__ int sh[256];
    int t = threadIdx.x, i = blockIdx.x * 256 + t;
    int v = (i < n) ? cnt[i] : 0;
    sh[t] = v;
    __syncthreads();
    for (int o = 1; o < 256; o <<= 1){
        int u = (t >= o) ? sh[t - o] : 0;
        __syncthreads();
        sh[t] += u;
        __syncthreads();
    }
    int incl = sh[t];
    if (i < n)     rowstart[i] = bsumoff[blockIdx.x] + incl - v;
    if (i == n-1)  rowstart[n] = bsumoff[blockIdx.x] + incl;
}

// ---------------------------------------------------------------------------
// k_scatter: recs[rowstart[d]+off[e]] = {src, w}  (no atomics)
__global__ void k_scatter(const int* __restrict__ ei, const void* __restrict__ ew,
                          const int* __restrict__ rowstart, const int* __restrict__ off,
                          int2* __restrict__ recs, const int* __restrict__ flags,
                          int E, int N){
    int e = blockIdx.x * 256 + threadIdx.x;
    if (e >= E) return;
    int fF = flags[0], fI = flags[1];
    int s, d;
    if (fI){ s = ei[2*(size_t)e]; d = ei[2*(size_t)E + 2*(size_t)e]; }
    else   { s = ei[e];           d = ei[(size_t)E + e]; }
    if ((unsigned)d >= (unsigned)N) return;
    float w = 0.f; int ss = 0;
    if ((unsigned)s < (unsigned)N){ w = ldsel(ew, e, fF); ss = s; }
    int2 r; r.x = ss; r.y = __float_as_int(w);
    recs[rowstart[d] + off[e]] = r;
}

// ---------------------------------------------------------------------------
// k_degdis: one wave per node, deg = sum of w over bin (coalesced), dis = rsqrt
__global__ __launch_bounds__(256)
void k_degdis(const int2* __restrict__ recs, const int* __restrict__ rowstart,
              float* __restrict__ dis, int N){
    int gw = (blockIdx.x * 256 + threadIdx.x) >> 6;
    int lane = threadIdx.x & 63;
    if (gw >= N) return;
    int beg = rowstart[gw], end = rowstart[gw + 1];
    float sw = 0.f;
    for (int i = beg + lane; i < end; i += 64) sw += __int_as_float(recs[i].y);
    for (int o = 32; o > 0; o >>= 1) sw += __shfl_down(sw, o);
    if (lane == 0) dis[gw] = (sw > 0.f) ? rsqrtf(sw) : 0.f;
}

// ---------------------------------------------------------------------------
// k_gather: 2 waves per node (wave = one 128-ch half: 0=X, 1=H).
// lane owns 2 channels (one uint of bf16x2). 2-edge unroll for ILP.
__global__ __launch_bounds__(256)
void k_gather(const int2* __restrict__ recs, const int* __restrict__ rowstart,
              const float* __restrict__ dis, const unsigned int* __restrict__ XHb32,
              unsigned int* __restrict__ AXH32, int N){
    int gw = (blockIdx.x * 256 + threadIdx.x) >> 6;
    int lane = threadIdx.x & 63;
    if (gw >= 2*N) return;
    int node = gw >> 1;
    int half = (gw & 1) * 64;
    int beg = rowstart[node], end = rowstart[node + 1];
    float disd = dis[node];
    float a0 = 0.f, a1 = 0.f;
    int i = beg;
    for (; i + 1 < end; i += 2){
        int2 r1 = recs[i];
        int2 r2 = recs[i+1];
        float n1 = dis[r1.x] * __int_as_float(r1.y) * disd;
        float n2 = dis[r2.x] * __int_as_float(r2.y) * disd;
        unsigned int v1 = XHb32[(size_t)r1.x*128 + half + lane];
        unsigned int v2 = XHb32[(size_t)r2.x*128 + half + lane];
        a0 += n1 * bf2f((unsigned short)(v1 & 0xffff));
        a1 += n1 * bf2f((unsigned short)(v1 >> 16));
        a0 += n2 * bf2f((unsigned short)(v2 & 0xffff));
        a1 += n2 * bf2f((unsigned short)(v2 >> 16));
    }
    if (i < end){
        int2 r1 = recs[i];
        float n1 = dis[r1.x] * __int_as_float(r1.y) * disd;
        unsigned int v1 = XHb32[(size_t)r1.x*128 + half + lane];
        a0 += n1 * bf2f((unsigned short)(v1 & 0xffff));
        a1 += n1 * bf2f((unsigned short)(v1 >> 16));
    }
    AXH32[(size_t)node*128 + half + lane] = ((unsigned int)f2bf(a1) << 16) | f2bf(a0);
}

// ---------------------------------------------------------------------------
struct EpiArgs {
    const void *C, *wci, *wcf, *wco, *bi, *bff, *bc, *bo;
};

// Fused GEMM + LSTM epilogue (R3-validated). Block = 4 waves; 16 nodes;
// wave g = gate g. A-fragments loaded directly from AXH (bf16 rows).
__global__ __launch_bounds__(256)
void k_gemm(const unsigned short* __restrict__ AXH,
            const unsigned short* __restrict__ Bp, const float* __restrict__ bias,
            EpiArgs ea, void* __restrict__ outp, const int* __restrict__ flags, int N){
    __shared__ float pre[4][16][132];

    int tid  = threadIdx.x;
    int wave = tid >> 6, lane = tid & 63;
    int node0 = blockIdx.x * 16;
    int fF = flags[0];

    f4v acc[8];
#pragma unroll
    for (int ct = 0; ct < 8; ct++) acc[ct] = (f4v){0.f,0.f,0.f,0.f};

    const int g = wave;
    const unsigned short* abase = AXH + (size_t)(node0 + (lane & 15))*256 + (lane >> 4)*8;
#pragma unroll
    for (int kb = 0; kb < 8; kb++){
        s8v af = *(const s8v*)(abase + kb*32);
        const unsigned short* bbase = Bp + g*32768 + kb*512 + lane*8;
#pragma unroll
        for (int ct = 0; ct < 8; ct++){
            s8v bfrag = *(const s8v*)(bbase + ct*4096);
            acc[ct] = __builtin_amdgcn_mfma_f32_16x16x32_bf16(af, bfrag, acc[ct], 0, 0, 0);
        }
    }

    // D layout: col = lane&15, row = (lane>>4)*4 + r
    int q = lane >> 4, cl = lane & 15;
#pragma unroll
    for (int ct = 0; ct < 8; ct++){
        int col = ct*16 + cl;
        float bv = bias[g*128 + col];
#pragma unroll
        for (int r = 0; r < 4; r++)
            pre[g][q*4 + r][col] = acc[ct][r] + bv;
    }
    __syncthreads();

    // LSTM cell epilogue
    for (int i = tid; i < 2048; i += 256){
        int nn = i >> 7, c = i & 127;
        if (node0 + nn >= N) break;
        size_t gidx = (size_t)(node0+nn)*128 + c;
        float Cv  = ldsel(ea.C, gidx, fF);
        float pi  = pre[0][nn][c], pf = pre[1][nn][c];
        float pcv = pre[2][nn][c], po = pre[3][nn][c];
        float Iv = sigm(pi + ldsel(ea.wci, c, fF)*Cv + ldsel(ea.bi, c, fF));
        float Fv = sigm(pf + ldsel(ea.wcf, c, fF)*Cv + ldsel(ea.bff, c, fF));
        float Tv = tanhf(pcv + ldsel(ea.bc, c, fF));
        float Cn = Fv*Cv + Iv*Tv;
        float Ov = sigm(po + ldsel(ea.wco, c, fF)*Cn + ldsel(ea.bo, c, fF));
        float Hn = Ov * tanhf(Cn);
        if (fF){
            ((float*)outp)[gidx] = Hn;
            ((float*)outp)[(size_t)N*128 + gidx] = Cn;
        } else {
            ((unsigned short*)outp)[gidx] = f2bf(Hn);
            ((unsigned short*)outp)[(size_t)N*128 + gidx] = f2bf(Cn);
        }
    }
}

// ---------------------------------------------------------------------------
extern "C" void kernel_launch(void* const* d_in, const int* in_sizes, int n_in,
                              void* d_out, int out_size, void* d_ws, size_t ws_size,
                              hipStream_t stream){
    const void* X  = d_in[0];
    const int*  ei = (const int*)d_in[1];
    const void* ew = d_in[2];
    const void* H  = d_in[3];
    const void* C  = d_in[4];
    const int N = in_sizes[0] / 128;
    const int E = in_sizes[2];

    // workspace layout (bytes), peak ~66.6 MB:
    // [0,256K) cnt | [256K,512K) dis | [512K,768K) rowstart
    // [768K] bsum(1K) | [772K] bsumoff(1K) | [776K] flags(8B)
    // [1M,1.25M) Bp | [1.25M] bias(2K)
    // [2M,8.4M) off (dead after k_scatter)
    // [2M,27.6M) AXH (aliases off; written by k_gather after scatter)
    // [28M,40.8M) recs | [41M,66.6M) XHb
    char* ws = (char*)d_ws;
    int*   cnt          = (int*)  (ws);
    float* dis          = (float*)(ws + ((size_t)256 << 10));
    int*   rowstart     = (int*)  (ws + ((size_t)512 << 10));
    int*   bsum         = (int*)  (ws + ((size_t)768 << 10));
    int*   bsumoff      = (int*)  (ws + ((size_t)772 << 10));
    int*   flags        = (int*)  (ws + ((size_t)776 << 10));
    unsigned short* Bp  = (unsigned short*)(ws + ((size_t)1 << 20));
    float* bias         = (float*)(ws + ((size_t)1 << 20) + ((size_t)256 << 10));
    int*   off          = (int*)  (ws + ((size_t)2 << 20));
    unsigned int* AXH32 = (unsigned int*)(ws + ((size_t)2 << 20));
    int2*  recs         = (int2*) (ws + ((size_t)28 << 20));
    unsigned int* XHb32 = (unsigned int*)(ws + ((size_t)41 << 20));

    hipMemsetAsync(cnt, 0, (size_t)256 << 10, stream);
    k_detect<<<1, 256, 0, stream>>>((const unsigned short*)X, ei, flags);

    PackArgs pa;
    pa.Wx[0]=d_in[5];  pa.bx[0]=d_in[6];  pa.Wh[0]=d_in[7];  pa.bh[0]=d_in[8];
    pa.Wx[1]=d_in[9];  pa.bx[1]=d_in[10]; pa.Wh[1]=d_in[11]; pa.bh[1]=d_in[12];
    pa.Wx[2]=d_in[13]; pa.bx[2]=d_in[14]; pa.Wh[2]=d_in[15]; pa.bh[2]=d_in[16];
    pa.Wx[3]=d_in[17]; pa.bx[3]=d_in[18]; pa.Wh[3]=d_in[19]; pa.bh[3]=d_in[20];

    int nbT = (N*64 + 255)/256;
    int nbC = (E + 255)/256;
    k_fused1<<<nbT + nbC + 512, 256, 0, stream>>>(X, H, XHb32, ei, cnt, off,
                                                  pa, Bp, bias, flags, nbT, nbC, E, N);

    int nbA = (N + 255)/256;
    k_scanA<<<nbA, 256, 0, stream>>>(cnt, bsum, N);
    k_scanB<<<1, 256, 0, stream>>>(bsum, bsumoff, nbA);
    k_scanC<<<nbA, 256, 0, stream>>>(cnt, bsumoff, rowstart, N);

    k_scatter<<<(E + 255)/256, 256, 0, stream>>>(ei, ew, rowstart, off, recs, flags, E, N);
    k_degdis<<<(N*64 + 255)/256, 256, 0, stream>>>(recs, rowstart, dis, N);
    k_gather<<<(2*N*64 + 255)/256, 256, 0, stream>>>(recs, rowstart, dis, XHb32, AXH32, N);

    EpiArgs ea;
    ea.C   = C;
    ea.wci = d_in[21];
    ea.wcf = d_in[22];
    ea.wco = d_in[23];
    ea.bi  = d_in[24];
    ea.bff = d_in[25];
    ea.bc  = d_in[26];
    ea.bo  = d_in[27];
    k_gemm<<<(N + 15)/16, 256, 0, stream>>>((const unsigned short*)AXH32, Bp, bias,
                                            ea, d_out, flags, N);
}